// Round 1
// baseline (346.715 us; speedup 1.0000x reference)
//
#include <hip/hip_runtime.h>

#define DEV __device__ __forceinline__

typedef __attribute__((ext_vector_type(4))) float f32x4;
typedef __attribute__((ext_vector_type(8))) short bf8v;   // 8 bf16 as shorts (4 VGPR)
typedef __attribute__((ext_vector_type(4))) unsigned short u16x4;
typedef __attribute__((ext_vector_type(8))) unsigned short u16x8;

static constexpr int LSEQ = 2048;
static constexpr int DIM  = 1024;
static constexpr int NH   = 16;
static constexpr int DH   = 64;
static constexpr int NB   = 4;
static constexpr int MROWS = NB * LSEQ;   // 8192
// SCALE * log2(e) folded into Q at projection time
static constexpr float QSCALE = 0.18033688011112042f;

DEV unsigned short f2bf(float x) {
  unsigned u = __float_as_uint(x);
  return (unsigned short)((u + 0x7fffu + ((u >> 16) & 1u)) >> 16);
}

DEV void gload_lds16(const void* g, void* l) {
  __builtin_amdgcn_global_load_lds((const __attribute__((address_space(1))) void*)g,
                                   (__attribute__((address_space(3))) void*)l, 16, 0, 0);
}

// ---------------- converts ----------------
__global__ __launch_bounds__(256) void k_cvt(const float* __restrict__ src,
                                             unsigned short* __restrict__ dst, int n) {
  int i = (blockIdx.x * 256 + threadIdx.x) * 8;
  if (i >= n) return;
  f32x4 a = *(const f32x4*)(src + i);
  f32x4 b = *(const f32x4*)(src + i + 4);
  u16x8 o;
  o[0] = f2bf(a[0]); o[1] = f2bf(a[1]); o[2] = f2bf(a[2]); o[3] = f2bf(a[3]);
  o[4] = f2bf(b[0]); o[5] = f2bf(b[1]); o[6] = f2bf(b[2]); o[7] = f2bf(b[3]);
  *(u16x8*)(dst + i) = o;
}

__global__ __launch_bounds__(256) void k_logr(const float* __restrict__ R,
                                              float* __restrict__ out,
                                              const float* __restrict__ beta, int n) {
  int i = (blockIdx.x * 256 + threadIdx.x) * 4;
  if (i >= n) return;
  float bb = beta[0];
  f32x4 r = *(const f32x4*)(R + i);
  f32x4 o;
  #pragma unroll
  for (int j = 0; j < 4; ++j) o[j] = bb * log2f(fmaxf(r[j], 1e-8f));
  *(f32x4*)(out + i) = o;
}

// ---------------- GEMM core: C[128x128] = A[m0..][1024] * B[n0..][1024]^T ----------------
DEV void gemm_core(const unsigned short* __restrict__ A, const unsigned short* __restrict__ Bm,
                   int m0, int n0, unsigned short* As, unsigned short* Bs, f32x4 (*acc)[4]) {
  const int tid = threadIdx.x;
  const int lane = tid & 63, wid = tid >> 6;
  const int g = lane >> 4, lq = lane & 15;
  const int wr = wid >> 1, wc = wid & 1;

  int aoff[2][4], boff[2][4];
  #pragma unroll
  for (int kk = 0; kk < 2; ++kk) {
    #pragma unroll
    for (int t = 0; t < 4; ++t) {
      aoff[kk][t] = (((wr * 64 + t * 16 + lq) * 128 + kk * 64 + g * 16) ^ ((lq & 7) << 4));
      boff[kk][t] = (((wc * 64 + t * 16 + lq) * 128 + kk * 64 + g * 16) ^ ((lq & 7) << 4));
    }
  }

  for (int kt = 0; kt < 16; ++kt) {
    #pragma unroll
    for (int i = 0; i < 4; ++i) {
      int chunk = i * 256 + tid;
      int row = chunk >> 3;
      int cc = (chunk & 7) ^ (row & 7);   // inverse swizzle on global source
      gload_lds16(A + (size_t)(m0 + row) * 1024 + kt * 64 + cc * 8, As + (i * 256 + wid * 64) * 8);
      gload_lds16(Bm + (size_t)(n0 + row) * 1024 + kt * 64 + cc * 8, Bs + (i * 256 + wid * 64) * 8);
    }
    __syncthreads();
    #pragma unroll
    for (int kk = 0; kk < 2; ++kk) {
      bf8v af[4], bfr[4];
      #pragma unroll
      for (int mi = 0; mi < 4; ++mi) af[mi] = *(const bf8v*)((const char*)As + aoff[kk][mi]);
      #pragma unroll
      for (int ni = 0; ni < 4; ++ni) bfr[ni] = *(const bf8v*)((const char*)Bs + boff[kk][ni]);
      #pragma unroll
      for (int mi = 0; mi < 4; ++mi)
        #pragma unroll
        for (int ni = 0; ni < 4; ++ni)
          acc[mi][ni] = __builtin_amdgcn_mfma_f32_16x16x32_bf16(af[mi], bfr[ni], acc[mi][ni], 0, 0, 0);
    }
    __syncthreads();
  }
}

// ---------------- QKV projection ----------------
__global__ __launch_bounds__(256) void k_gemm_qkv(
    const unsigned short* __restrict__ A, const unsigned short* __restrict__ W,
    unsigned short* __restrict__ Qb, unsigned short* __restrict__ Kb,
    unsigned short* __restrict__ Vt) {
  __shared__ unsigned short As[128 * 64];
  __shared__ unsigned short Bs[128 * 64];
  f32x4 acc[4][4];
  f32x4 z = {0.f, 0.f, 0.f, 0.f};
  #pragma unroll
  for (int mi = 0; mi < 4; ++mi)
    #pragma unroll
    for (int ni = 0; ni < 4; ++ni) acc[mi][ni] = z;

  const int m0 = blockIdx.x * 128, n0 = blockIdx.y * 128;
  gemm_core(A, W, m0, n0, As, Bs, acc);

  const int tid = threadIdx.x;
  const int lane = tid & 63, wid = tid >> 6;
  const int g = lane >> 4, lq = lane & 15;
  const int wr = wid >> 1, wc = wid & 1;
  const int region = n0 >> 10;          // 0=Q 1=K 2=V
  const int nrel0 = n0 & 1023;

  if (region < 2) {
    unsigned short* dst = (region == 0) ? Qb : Kb;
    const float sc = (region == 0) ? QSCALE : 1.0f;
    #pragma unroll
    for (int mi = 0; mi < 4; ++mi)
      #pragma unroll
      for (int ni = 0; ni < 4; ++ni) {
        int m = m0 + wr * 64 + mi * 16 + g * 4;
        int n = nrel0 + wc * 64 + ni * 16 + lq;
        int b = m >> 11, l = m & 2047;
        int h = n >> 6, d = n & 63;
        int base = ((b * NH + h) * LSEQ + l) * DH + d;
        #pragma unroll
        for (int r = 0; r < 4; ++r)
          dst[base + r * DH] = f2bf(acc[mi][ni][r] * sc);
      }
  } else {
    #pragma unroll
    for (int mi = 0; mi < 4; ++mi)
      #pragma unroll
      for (int ni = 0; ni < 4; ++ni) {
        int m = m0 + wr * 64 + mi * 16 + g * 4;
        int n = nrel0 + wc * 64 + ni * 16 + lq;
        int b = m >> 11, l = m & 2047;
        int h = n >> 6, d = n & 63;
        u16x4 pk;
        #pragma unroll
        for (int r = 0; r < 4; ++r) pk[r] = f2bf(acc[mi][ni][r]);
        *(u16x4*)(Vt + (size_t)((b * NH + h) * DH + d) * LSEQ + l) = pk;  // V transposed
      }
  }
}

// ---------------- flash attention, swapped-operand (S^T = K Q^T) ----------------
__global__ __launch_bounds__(256) void k_attn(
    const unsigned short* __restrict__ Qb, const unsigned short* __restrict__ Kb,
    const unsigned short* __restrict__ Vt, const float* __restrict__ logr,
    unsigned short* __restrict__ AO) {
  __shared__ unsigned short Ks[64 * 64];
  __shared__ unsigned short Vs[64 * 64];
  __shared__ unsigned short Ps[4][32 * 64];
  const int tid = threadIdx.x;
  const int lane = tid & 63, wid = tid >> 6;
  const int g = lane >> 4, lq = lane & 15;
  const int bh = blockIdx.y;
  const int q0 = blockIdx.x * 128;
  const int b = bh >> 4, h = bh & 15;
  const unsigned short* Qbh = Qb + (size_t)bh * LSEQ * DH;
  const unsigned short* Kbh = Kb + (size_t)bh * LSEQ * DH;
  const unsigned short* Vbh = Vt + (size_t)bh * DH * LSEQ;
  const int qw = q0 + wid * 32;

  // Q fragments live in registers (already scaled by SCALE*log2e)
  bf8v qf[2][2];
  #pragma unroll
  for (int qi = 0; qi < 2; ++qi)
    #pragma unroll
    for (int kk = 0; kk < 2; ++kk)
      qf[qi][kk] = *(const bf8v*)(Qbh + (size_t)(qw + qi * 16 + lq) * DH + kk * 32 + g * 8);

  f32x4 oacc[4][2];
  f32x4 z = {0.f, 0.f, 0.f, 0.f};
  #pragma unroll
  for (int db = 0; db < 4; ++db)
    #pragma unroll
    for (int qi = 0; qi < 2; ++qi) oacc[db][qi] = z;
  float mrun[2] = {-__builtin_inff(), -__builtin_inff()};
  float lrun[2] = {0.f, 0.f};

  const float* lr0 = logr + (size_t)(qw + lq) * LSEQ;
  const float* lr1 = logr + (size_t)(qw + 16 + lq) * LSEQ;

  for (int t = 0; t < 32; ++t) {
    // bias tile = MFMA C-initializer (beta*log2R already scaled)
    f32x4 sac[4][2];
    #pragma unroll
    for (int kb = 0; kb < 4; ++kb) {
      sac[kb][0] = *(const f32x4*)(lr0 + t * 64 + kb * 16 + g * 4);
      sac[kb][1] = *(const f32x4*)(lr1 + t * 64 + kb * 16 + g * 4);
    }
    // stage K[64x64] and V^T[64x64] tiles
    #pragma unroll
    for (int i = 0; i < 2; ++i) {
      int chunk = i * 256 + tid;
      int row = chunk >> 3;
      int cc = (chunk & 7) ^ (row & 7);
      gload_lds16(Kbh + (size_t)(t * 64 + row) * DH + cc * 8, Ks + (i * 256 + wid * 64) * 8);
      gload_lds16(Vbh + (size_t)row * LSEQ + t * 64 + cc * 8, Vs + (i * 256 + wid * 64) * 8);
    }
    __syncthreads();

    // S^T[k,q] = K Q^T  (+bias init)
    #pragma unroll
    for (int kk = 0; kk < 2; ++kk) {
      bf8v kf[4];
      #pragma unroll
      for (int kb = 0; kb < 4; ++kb)
        kf[kb] = *(const bf8v*)((const char*)Ks +
                  ((((kb * 16 + lq) * 128) + kk * 64 + g * 16) ^ ((lq & 7) << 4)));
      #pragma unroll
      for (int kb = 0; kb < 4; ++kb)
        #pragma unroll
        for (int qi = 0; qi < 2; ++qi)
          sac[kb][qi] = __builtin_amdgcn_mfma_f32_16x16x32_bf16(kf[kb], qf[qi][kk], sac[kb][qi], 0, 0, 0);
    }

    // online softmax (per lane: one q column; reduce over 16 reg + 2 shuffles)
    #pragma unroll
    for (int qi = 0; qi < 2; ++qi) {
      float mx = sac[0][qi][0];
      #pragma unroll
      for (int kb = 0; kb < 4; ++kb)
        #pragma unroll
        for (int r = 0; r < 4; ++r) mx = fmaxf(mx, sac[kb][qi][r]);
      mx = fmaxf(mx, __shfl_xor(mx, 16));
      mx = fmaxf(mx, __shfl_xor(mx, 32));
      float mnew = fmaxf(mrun[qi], mx);
      float corr = exp2f(mrun[qi] - mnew);
      mrun[qi] = mnew;
      float ls = 0.f;
      #pragma unroll
      for (int kb = 0; kb < 4; ++kb) {
        u16x4 pk;
        #pragma unroll
        for (int r = 0; r < 4; ++r) {
          float p = exp2f(sac[kb][qi][r] - mnew);
          ls += p;
          pk[r] = f2bf(p);
        }
        *(u16x4*)((char*)(Ps[wid]) +
                  ((((qi * 16 + lq) * 128) + kb * 32 + g * 8) ^ ((lq & 7) << 4))) = pk;
      }
      ls += __shfl_xor(ls, 16);
      ls += __shfl_xor(ls, 32);
      lrun[qi] = lrun[qi] * corr + ls;
      #pragma unroll
      for (int db = 0; db < 4; ++db)
        #pragma unroll
        for (int r = 0; r < 4; ++r) oacc[db][qi][r] *= corr;
    }
    asm volatile("" ::: "memory");   // order P-writes before P-reads at IR level

    // O^T[d,q] += V^T P^T
    #pragma unroll
    for (int kw = 0; kw < 2; ++kw) {
      bf8v vf[4], pf[2];
      #pragma unroll
      for (int db = 0; db < 4; ++db)
        vf[db] = *(const bf8v*)((const char*)Vs +
                  ((((db * 16 + lq) * 128) + kw * 64 + g * 16) ^ ((lq & 7) << 4)));
      #pragma unroll
      for (int qi = 0; qi < 2; ++qi) {
        int byt = (((qi * 16 + lq) * 128) + kw * 64 + g * 16) ^ ((lq & 7) << 4);
        u16x4 lo = *(const u16x4*)((const char*)(Ps[wid]) + byt);
        u16x4 hi = *(const u16x4*)((const char*)(Ps[wid]) + (byt + 8));
        union { u16x4 hh[2]; bf8v v; } u;
        u.hh[0] = lo; u.hh[1] = hi;
        pf[qi] = u.v;
      }
      #pragma unroll
      for (int db = 0; db < 4; ++db)
        #pragma unroll
        for (int qi = 0; qi < 2; ++qi)
          oacc[db][qi] = __builtin_amdgcn_mfma_f32_16x16x32_bf16(vf[db], pf[qi], oacc[db][qi], 0, 0, 0);
    }
    __syncthreads();
  }

  #pragma unroll
  for (int qi = 0; qi < 2; ++qi) {
    float inv = 1.f / lrun[qi];
    int q = qw + qi * 16 + lq;
    #pragma unroll
    for (int db = 0; db < 4; ++db) {
      u16x4 pk;
      #pragma unroll
      for (int r = 0; r < 4; ++r) pk[r] = f2bf(oacc[db][qi][r] * inv);
      int d = db * 16 + g * 4;
      *(u16x4*)(AO + (size_t)(b * LSEQ + q) * DIM + h * DH + d) = pk;
    }
  }
}

// ---------------- output projection + residual ----------------
__global__ __launch_bounds__(256) void k_gemm_proj(
    const unsigned short* __restrict__ A, const unsigned short* __restrict__ W,
    const float* __restrict__ res, float* __restrict__ out) {
  __shared__ unsigned short As[128 * 64];
  __shared__ unsigned short Bs[128 * 64];
  f32x4 acc[4][4];
  f32x4 z = {0.f, 0.f, 0.f, 0.f};
  #pragma unroll
  for (int mi = 0; mi < 4; ++mi)
    #pragma unroll
    for (int ni = 0; ni < 4; ++ni) acc[mi][ni] = z;

  const int m0 = blockIdx.x * 128, n0 = blockIdx.y * 128;
  gemm_core(A, W, m0, n0, As, Bs, acc);

  const int tid = threadIdx.x;
  const int lane = tid & 63, wid = tid >> 6;
  const int g = lane >> 4, lq = lane & 15;
  const int wr = wid >> 1, wc = wid & 1;
  #pragma unroll
  for (int mi = 0; mi < 4; ++mi)
    #pragma unroll
    for (int ni = 0; ni < 4; ++ni) {
      int m = m0 + wr * 64 + mi * 16 + g * 4;
      int n = n0 + wc * 64 + ni * 16 + lq;
      #pragma unroll
      for (int r = 0; r < 4; ++r) {
        int idx = (m + r) * 1024 + n;
        out[idx] = acc[mi][ni][r] + res[idx];
      }
    }
}

// ---------------- in-place LayerNorm on d_out ----------------
__global__ __launch_bounds__(256) void k_ln(float* __restrict__ x,
                                            const float* __restrict__ gamma,
                                            const float* __restrict__ bias) {
  const int row = blockIdx.x;
  const int tid = threadIdx.x;
  float* xr = x + (size_t)row * 1024;
  f32x4 v = *(f32x4*)(xr + tid * 4);
  float s = v[0] + v[1] + v[2] + v[3];
  float ss = v[0] * v[0] + v[1] * v[1] + v[2] * v[2] + v[3] * v[3];
  #pragma unroll
  for (int off = 1; off < 64; off <<= 1) {
    s += __shfl_xor(s, off);
    ss += __shfl_xor(ss, off);
  }
  __shared__ float red[8];
  const int lane = tid & 63, wid = tid >> 6;
  if (lane == 0) { red[wid] = s; red[wid + 4] = ss; }
  __syncthreads();
  s = red[0] + red[1] + red[2] + red[3];
  ss = red[4] + red[5] + red[6] + red[7];
  float mu = s * (1.f / 1024.f);
  float var = ss * (1.f / 1024.f) - mu * mu;
  float rs = rsqrtf(var + 1e-5f);
  f32x4 gm = *(const f32x4*)(gamma + tid * 4);
  f32x4 bi = *(const f32x4*)(bias + tid * 4);
  f32x4 o;
  #pragma unroll
  for (int j = 0; j < 4; ++j) o[j] = (v[j] - mu) * rs * gm[j] + bi[j];
  *(f32x4*)(xr + tid * 4) = o;
}

extern "C" void kernel_launch(void* const* d_in, const int* in_sizes, int n_in,
                              void* d_out, int out_size, void* d_ws, size_t ws_size,
                              hipStream_t stream) {
  const float* tokens = (const float*)d_in[0];
  const float* R      = (const float*)d_in[1];
  const float* Wq     = (const float*)d_in[2];
  const float* Wk     = (const float*)d_in[3];
  const float* Wv     = (const float*)d_in[4];
  const float* Wp     = (const float*)d_in[5];
  const float* beta   = (const float*)d_in[6];
  const float* gamma  = (const float*)d_in[7];
  const float* bias   = (const float*)d_in[8];
  float* out = (float*)d_out;
  char* ws = (char*)d_ws;

  unsigned short* tok_bf = (unsigned short*)(ws);                 // 16,777,216 B
  unsigned short* wqkv   = (unsigned short*)(ws + 16777216);      //  6,291,456 B
  unsigned short* wp     = (unsigned short*)(ws + 23068672);      //  2,097,152 B
  float*          logr   = (float*)(ws + 25165824);               // 16,777,216 B
  unsigned short* qb     = (unsigned short*)(ws + 41943040);      // 16,777,216 B
  unsigned short* kb     = (unsigned short*)(ws + 58720256);      // 16,777,216 B
  unsigned short* vt     = (unsigned short*)(ws + 75497472);      // 16,777,216 B
  unsigned short* ao     = tok_bf;  // reuse: tok_bf dead after QKV GEMM

  k_cvt<<<4096, 256, 0, stream>>>(tokens, tok_bf, MROWS * DIM);
  k_cvt<<<512, 256, 0, stream>>>(Wq, wqkv, DIM * DIM);
  k_cvt<<<512, 256, 0, stream>>>(Wk, wqkv + DIM * DIM, DIM * DIM);
  k_cvt<<<512, 256, 0, stream>>>(Wv, wqkv + 2 * DIM * DIM, DIM * DIM);
  k_cvt<<<512, 256, 0, stream>>>(Wp, wp, DIM * DIM);
  k_logr<<<4096, 256, 0, stream>>>(R, logr, beta, LSEQ * LSEQ);

  k_gemm_qkv<<<dim3(64, 24), 256, 0, stream>>>(tok_bf, wqkv, qb, kb, vt);
  k_attn<<<dim3(16, 64), 256, 0, stream>>>(qb, kb, vt, logr, ao);
  k_gemm_proj<<<dim3(64, 8), 256, 0, stream>>>(ao, wp, tokens, out);
  k_ln<<<8192, 256, 0, stream>>>(out, gamma, bias);
}

// Round 2
// 304.890 us; speedup vs baseline: 1.1372x; 1.1372x over previous
//
#include <hip/hip_runtime.h>

#define DEV __device__ __forceinline__

typedef __attribute__((ext_vector_type(4))) float f32x4;
typedef __attribute__((ext_vector_type(8))) short bf8v;   // 8 bf16 as shorts (4 VGPR)
typedef __attribute__((ext_vector_type(4))) unsigned short u16x4;
typedef __attribute__((ext_vector_type(8))) unsigned short u16x8;
typedef __attribute__((ext_vector_type(2))) unsigned int u32x2;

static constexpr int LSEQ = 2048;
static constexpr int DIM  = 1024;
static constexpr int NH   = 16;
static constexpr int DH   = 64;
static constexpr int NB   = 4;
static constexpr int MROWS = NB * LSEQ;   // 8192
// SCALE * log2(e) folded into Q at projection time
static constexpr float QSCALE = 0.18033688011112042f;

DEV unsigned short f2bf(float x) {
  unsigned u = __float_as_uint(x);
  return (unsigned short)((u + 0x7fffu + ((u >> 16) & 1u)) >> 16);
}

DEV unsigned cvt_pk_bf16(float a, float b) {   // D.lo = bf16(a), D.hi = bf16(b)
  unsigned r;
  asm("v_cvt_pk_bf16_f32 %0, %1, %2" : "=v"(r) : "v"(a), "v"(b));
  return r;
}

DEV float fexp2(float x) {
  float r;
  asm("v_exp_f32 %0, %1" : "=v"(r) : "v"(x));
  return r;
}

DEV void gload_lds16(const void* g, void* l) {
  __builtin_amdgcn_global_load_lds((const __attribute__((address_space(1))) void*)g,
                                   (__attribute__((address_space(3))) void*)l, 16, 0, 0);
}

// ---------------- converts ----------------
__global__ __launch_bounds__(256) void k_cvt(const float* __restrict__ src,
                                             unsigned short* __restrict__ dst, int n) {
  int i = (blockIdx.x * 256 + threadIdx.x) * 8;
  if (i >= n) return;
  f32x4 a = *(const f32x4*)(src + i);
  f32x4 b = *(const f32x4*)(src + i + 4);
  u16x8 o;
  o[0] = f2bf(a[0]); o[1] = f2bf(a[1]); o[2] = f2bf(a[2]); o[3] = f2bf(a[3]);
  o[4] = f2bf(b[0]); o[5] = f2bf(b[1]); o[6] = f2bf(b[2]); o[7] = f2bf(b[3]);
  *(u16x8*)(dst + i) = o;
}

__global__ __launch_bounds__(256) void k_logr(const float* __restrict__ R,
                                              float* __restrict__ out,
                                              const float* __restrict__ beta, int n) {
  int i = (blockIdx.x * 256 + threadIdx.x) * 4;
  if (i >= n) return;
  float bb = beta[0];
  f32x4 r = *(const f32x4*)(R + i);
  f32x4 o;
  #pragma unroll
  for (int j = 0; j < 4; ++j) o[j] = bb * log2f(fmaxf(r[j], 1e-8f));
  *(f32x4*)(out + i) = o;
}

// ---------------- GEMM core: C[128x128] = A[m0..][1024] * B[n0..][1024]^T ----------------
DEV void gemm_core(const unsigned short* __restrict__ A, const unsigned short* __restrict__ Bm,
                   int m0, int n0, unsigned short* As, unsigned short* Bs, f32x4 (*acc)[4]) {
  const int tid = threadIdx.x;
  const int lane = tid & 63, wid = tid >> 6;
  const int g = lane >> 4, lq = lane & 15;
  const int wr = wid >> 1, wc = wid & 1;

  int aoff[2][4], boff[2][4];
  #pragma unroll
  for (int kk = 0; kk < 2; ++kk) {
    #pragma unroll
    for (int t = 0; t < 4; ++t) {
      aoff[kk][t] = (((wr * 64 + t * 16 + lq) * 128 + kk * 64 + g * 16) ^ ((lq & 7) << 4));
      boff[kk][t] = (((wc * 64 + t * 16 + lq) * 128 + kk * 64 + g * 16) ^ ((lq & 7) << 4));
    }
  }

  for (int kt = 0; kt < 16; ++kt) {
    #pragma unroll
    for (int i = 0; i < 4; ++i) {
      int chunk = i * 256 + tid;
      int row = chunk >> 3;
      int cc = (chunk & 7) ^ (row & 7);   // inverse swizzle on global source
      gload_lds16(A + (size_t)(m0 + row) * 1024 + kt * 64 + cc * 8, As + (i * 256 + wid * 64) * 8);
      gload_lds16(Bm + (size_t)(n0 + row) * 1024 + kt * 64 + cc * 8, Bs + (i * 256 + wid * 64) * 8);
    }
    __syncthreads();
    #pragma unroll
    for (int kk = 0; kk < 2; ++kk) {
      bf8v af[4], bfr[4];
      #pragma unroll
      for (int mi = 0; mi < 4; ++mi) af[mi] = *(const bf8v*)((const char*)As + aoff[kk][mi]);
      #pragma unroll
      for (int ni = 0; ni < 4; ++ni) bfr[ni] = *(const bf8v*)((const char*)Bs + boff[kk][ni]);
      #pragma unroll
      for (int mi = 0; mi < 4; ++mi)
        #pragma unroll
        for (int ni = 0; ni < 4; ++ni)
          acc[mi][ni] = __builtin_amdgcn_mfma_f32_16x16x32_bf16(af[mi], bfr[ni], acc[mi][ni], 0, 0, 0);
    }
    __syncthreads();
  }
}

// ---------------- QKV projection ----------------
__global__ __launch_bounds__(256) void k_gemm_qkv(
    const unsigned short* __restrict__ A, const unsigned short* __restrict__ W,
    unsigned short* __restrict__ Qb, unsigned short* __restrict__ Kb,
    unsigned short* __restrict__ Vt) {
  __shared__ unsigned short As[128 * 64];
  __shared__ unsigned short Bs[128 * 64];
  f32x4 acc[4][4];
  f32x4 z = {0.f, 0.f, 0.f, 0.f};
  #pragma unroll
  for (int mi = 0; mi < 4; ++mi)
    #pragma unroll
    for (int ni = 0; ni < 4; ++ni) acc[mi][ni] = z;

  const int m0 = blockIdx.x * 128, n0 = blockIdx.y * 128;
  gemm_core(A, W, m0, n0, As, Bs, acc);

  const int tid = threadIdx.x;
  const int lane = tid & 63, wid = tid >> 6;
  const int g = lane >> 4, lq = lane & 15;
  const int wr = wid >> 1, wc = wid & 1;
  const int region = n0 >> 10;          // 0=Q 1=K 2=V
  const int nrel0 = n0 & 1023;

  if (region < 2) {
    unsigned short* dst = (region == 0) ? Qb : Kb;
    const float sc = (region == 0) ? QSCALE : 1.0f;
    #pragma unroll
    for (int mi = 0; mi < 4; ++mi)
      #pragma unroll
      for (int ni = 0; ni < 4; ++ni) {
        int m = m0 + wr * 64 + mi * 16 + g * 4;
        int n = nrel0 + wc * 64 + ni * 16 + lq;
        int b = m >> 11, l = m & 2047;
        int h = n >> 6, d = n & 63;
        int base = ((b * NH + h) * LSEQ + l) * DH + d;
        #pragma unroll
        for (int r = 0; r < 4; ++r)
          dst[base + r * DH] = f2bf(acc[mi][ni][r] * sc);
      }
  } else {
    #pragma unroll
    for (int mi = 0; mi < 4; ++mi)
      #pragma unroll
      for (int ni = 0; ni < 4; ++ni) {
        int m = m0 + wr * 64 + mi * 16 + g * 4;
        int n = nrel0 + wc * 64 + ni * 16 + lq;
        int b = m >> 11, l = m & 2047;
        int h = n >> 6, d = n & 63;
        u16x4 pk;
        #pragma unroll
        for (int r = 0; r < 4; ++r) pk[r] = f2bf(acc[mi][ni][r]);
        *(u16x4*)(Vt + (size_t)((b * NH + h) * DH + d) * LSEQ + l) = pk;  // V transposed
      }
  }
}

// ---------------- flash attention, swapped-operand (S^T = K Q^T) ----------------
__global__ __launch_bounds__(256) void k_attn(
    const unsigned short* __restrict__ Qb, const unsigned short* __restrict__ Kb,
    const unsigned short* __restrict__ Vt, const float* __restrict__ logr,
    unsigned short* __restrict__ AO) {
  __shared__ unsigned short Ks[2][64 * 64];
  __shared__ unsigned short Vs[2][64 * 64];
  __shared__ unsigned short Ps[4][32 * 64];
  const int tid = threadIdx.x;
  const int lane = tid & 63, wid = tid >> 6;
  const int g = lane >> 4, lq = lane & 15;
  const int bh = blockIdx.y;
  const int q0 = blockIdx.x * 128;
  const int b = bh >> 4, h = bh & 15;
  const unsigned short* Qbh = Qb + (size_t)bh * LSEQ * DH;
  const unsigned short* Kbh = Kb + (size_t)bh * LSEQ * DH;
  const unsigned short* Vbh = Vt + (size_t)bh * DH * LSEQ;
  const int qw = q0 + wid * 32;

  // Q fragments live in registers (already scaled by SCALE*log2e)
  bf8v qf[2][2];
  #pragma unroll
  for (int qi = 0; qi < 2; ++qi)
    #pragma unroll
    for (int kk = 0; kk < 2; ++kk)
      qf[qi][kk] = *(const bf8v*)(Qbh + (size_t)(qw + qi * 16 + lq) * DH + kk * 32 + g * 8);

  f32x4 oacc[4][2];
  f32x4 z = {0.f, 0.f, 0.f, 0.f};
  #pragma unroll
  for (int db = 0; db < 4; ++db)
    #pragma unroll
    for (int qi = 0; qi < 2; ++qi) oacc[db][qi] = z;
  float mrun[2] = {-__builtin_inff(), -__builtin_inff()};
  float lrun[2] = {0.f, 0.f};

  const float* lr0 = logr + (size_t)(qw + lq) * LSEQ;
  const float* lr1 = logr + (size_t)(qw + 16 + lq) * LSEQ;

  // ---- prologue: stage tile 0 (buf 0) + bias(0) into regs ----
  #pragma unroll
  for (int i = 0; i < 2; ++i) {
    int chunk = i * 256 + tid;
    int row = chunk >> 3;
    int cc = (chunk & 7) ^ (row & 7);
    gload_lds16(Kbh + (size_t)row * DH + cc * 8, &Ks[0][(i * 256 + wid * 64) * 8]);
    gload_lds16(Vbh + (size_t)row * LSEQ + cc * 8, &Vs[0][(i * 256 + wid * 64) * 8]);
  }
  f32x4 sac[4][2];
  #pragma unroll
  for (int kb = 0; kb < 4; ++kb) {
    sac[kb][0] = *(const f32x4*)(lr0 + kb * 16 + g * 4);
    sac[kb][1] = *(const f32x4*)(lr1 + kb * 16 + g * 4);
  }
  __syncthreads();   // drains vmcnt (compiler emits full waitcnt before s_barrier)

  auto TILE = [&](int t, int buf, bool pref) {
    // prefetch K/V tile t+1 into the other buffer (latency hides under this tile)
    if (pref) {
      #pragma unroll
      for (int i = 0; i < 2; ++i) {
        int chunk = i * 256 + tid;
        int row = chunk >> 3;
        int cc = (chunk & 7) ^ (row & 7);
        gload_lds16(Kbh + (size_t)((t + 1) * 64 + row) * DH + cc * 8,
                    &Ks[buf ^ 1][(i * 256 + wid * 64) * 8]);
        gload_lds16(Vbh + (size_t)row * LSEQ + (t + 1) * 64 + cc * 8,
                    &Vs[buf ^ 1][(i * 256 + wid * 64) * 8]);
      }
    }

    // S^T = K Q^T, C-init = beta*log2R bias (already in sac)
    __builtin_amdgcn_s_setprio(1);
    #pragma unroll
    for (int kk = 0; kk < 2; ++kk) {
      bf8v kf[4];
      #pragma unroll
      for (int kb = 0; kb < 4; ++kb)
        kf[kb] = *(const bf8v*)((const char*)Ks[buf] +
                  ((((kb * 16 + lq) * 128) + kk * 64 + g * 16) ^ ((lq & 7) << 4)));
      #pragma unroll
      for (int kb = 0; kb < 4; ++kb)
        #pragma unroll
        for (int qi = 0; qi < 2; ++qi)
          sac[kb][qi] = __builtin_amdgcn_mfma_f32_16x16x32_bf16(kf[kb], qf[qi][kk], sac[kb][qi], 0, 0, 0);
    }
    __builtin_amdgcn_s_setprio(0);

    // column max (per lane: one q column) — tree + 2 shuffles
    float mx[2];
    #pragma unroll
    for (int qi = 0; qi < 2; ++qi) {
      float m0 = fmaxf(fmaxf(sac[0][qi][0], sac[0][qi][1]), fmaxf(sac[0][qi][2], sac[0][qi][3]));
      float m1 = fmaxf(fmaxf(sac[1][qi][0], sac[1][qi][1]), fmaxf(sac[1][qi][2], sac[1][qi][3]));
      float m2 = fmaxf(fmaxf(sac[2][qi][0], sac[2][qi][1]), fmaxf(sac[2][qi][2], sac[2][qi][3]));
      float m3 = fmaxf(fmaxf(sac[3][qi][0], sac[3][qi][1]), fmaxf(sac[3][qi][2], sac[3][qi][3]));
      float m = fmaxf(fmaxf(m0, m1), fmaxf(m2, m3));
      m = fmaxf(m, __shfl_xor(m, 16));
      m = fmaxf(m, __shfl_xor(m, 32));
      mx[qi] = m;
    }

    // defer-max (T13): rescale only when the running max grew by > 8 (exp2 units)
    if (__any((mx[0] > mrun[0] + 8.f) || (mx[1] > mrun[1] + 8.f))) {
      #pragma unroll
      for (int qi = 0; qi < 2; ++qi) {
        float mnew = fmaxf(mrun[qi], mx[qi]);
        float corr = fexp2(mrun[qi] - mnew);
        mrun[qi] = mnew;
        lrun[qi] *= corr;
        #pragma unroll
        for (int db = 0; db < 4; ++db)
          #pragma unroll
          for (int r = 0; r < 4; ++r) oacc[db][qi][r] *= corr;
      }
    }

    // P = exp2(S - m): pack via v_cvt_pk_bf16_f32, store 8B per (qi,kb)
    #pragma unroll
    for (int qi = 0; qi < 2; ++qi) {
      float mr = mrun[qi];
      float ls = 0.f;
      #pragma unroll
      for (int kb = 0; kb < 4; ++kb) {
        float p0 = fexp2(sac[kb][qi][0] - mr);
        float p1 = fexp2(sac[kb][qi][1] - mr);
        float p2 = fexp2(sac[kb][qi][2] - mr);
        float p3 = fexp2(sac[kb][qi][3] - mr);
        ls += (p0 + p1) + (p2 + p3);
        u32x2 w;
        w[0] = cvt_pk_bf16(p0, p1);
        w[1] = cvt_pk_bf16(p2, p3);
        *(u32x2*)((char*)Ps[wid] +
                  ((((qi * 16 + lq) * 128) + kb * 32 + g * 8) ^ ((lq & 7) << 4))) = w;
      }
      ls += __shfl_xor(ls, 16);
      ls += __shfl_xor(ls, 32);
      lrun[qi] += ls;
    }

    // bias prefetch for t+1 into sac (registers are dead now; hides under PV)
    if (pref) {
      #pragma unroll
      for (int kb = 0; kb < 4; ++kb) {
        sac[kb][0] = *(const f32x4*)(lr0 + (t + 1) * 64 + kb * 16 + g * 4);
        sac[kb][1] = *(const f32x4*)(lr1 + (t + 1) * 64 + kb * 16 + g * 4);
      }
    }
    asm volatile("" ::: "memory");   // order P-writes before P-reads at IR level

    // O^T[d,q] += V^T P^T
    __builtin_amdgcn_s_setprio(1);
    #pragma unroll
    for (int kw = 0; kw < 2; ++kw) {
      bf8v vf[4], pf[2];
      #pragma unroll
      for (int db = 0; db < 4; ++db)
        vf[db] = *(const bf8v*)((const char*)Vs[buf] +
                  ((((db * 16 + lq) * 128) + kw * 64 + g * 16) ^ ((lq & 7) << 4)));
      #pragma unroll
      for (int qi = 0; qi < 2; ++qi)
        pf[qi] = *(const bf8v*)((const char*)Ps[wid] +
                  ((((qi * 16 + lq) * 128) + kw * 64 + g * 16) ^ ((lq & 7) << 4)));
      #pragma unroll
      for (int db = 0; db < 4; ++db)
        #pragma unroll
        for (int qi = 0; qi < 2; ++qi)
          oacc[db][qi] = __builtin_amdgcn_mfma_f32_16x16x32_bf16(vf[db], pf[qi], oacc[db][qi], 0, 0, 0);
    }
    __builtin_amdgcn_s_setprio(0);
    __syncthreads();   // one barrier per tile: full drain covers the t+1 staging
  };

  for (int tp = 0; tp < 16; ++tp) {
    TILE(2 * tp,     0, true);
    TILE(2 * tp + 1, 1, tp != 15);
  }

  #pragma unroll
  for (int qi = 0; qi < 2; ++qi) {
    float inv = 1.f / lrun[qi];
    int q = qw + qi * 16 + lq;
    #pragma unroll
    for (int db = 0; db < 4; ++db) {
      u32x2 w;
      w[0] = cvt_pk_bf16(oacc[db][qi][0] * inv, oacc[db][qi][1] * inv);
      w[1] = cvt_pk_bf16(oacc[db][qi][2] * inv, oacc[db][qi][3] * inv);
      int d = db * 16 + g * 4;
      *(u32x2*)(AO + (size_t)(b * LSEQ + q) * DIM + h * DH + d) = w;
    }
  }
}

// ---------------- output projection + residual ----------------
__global__ __launch_bounds__(256) void k_gemm_proj(
    const unsigned short* __restrict__ A, const unsigned short* __restrict__ W,
    const float* __restrict__ res, float* __restrict__ out) {
  __shared__ unsigned short As[128 * 64];
  __shared__ unsigned short Bs[128 * 64];
  f32x4 acc[4][4];
  f32x4 z = {0.f, 0.f, 0.f, 0.f};
  #pragma unroll
  for (int mi = 0; mi < 4; ++mi)
    #pragma unroll
    for (int ni = 0; ni < 4; ++ni) acc[mi][ni] = z;

  const int m0 = blockIdx.x * 128, n0 = blockIdx.y * 128;
  gemm_core(A, W, m0, n0, As, Bs, acc);

  const int tid = threadIdx.x;
  const int lane = tid & 63, wid = tid >> 6;
  const int g = lane >> 4, lq = lane & 15;
  const int wr = wid >> 1, wc = wid & 1;
  #pragma unroll
  for (int mi = 0; mi < 4; ++mi)
    #pragma unroll
    for (int ni = 0; ni < 4; ++ni) {
      int m = m0 + wr * 64 + mi * 16 + g * 4;
      int n = n0 + wc * 64 + ni * 16 + lq;
      #pragma unroll
      for (int r = 0; r < 4; ++r) {
        int idx = (m + r) * 1024 + n;
        out[idx] = acc[mi][ni][r] + res[idx];
      }
    }
}

// ---------------- in-place LayerNorm on d_out ----------------
__global__ __launch_bounds__(256) void k_ln(float* __restrict__ x,
                                            const float* __restrict__ gamma,
                                            const float* __restrict__ bias) {
  const int row = blockIdx.x;
  const int tid = threadIdx.x;
  float* xr = x + (size_t)row * 1024;
  f32x4 v = *(f32x4*)(xr + tid * 4);
  float s = v[0] + v[1] + v[2] + v[3];
  float ss = v[0] * v[0] + v[1] * v[1] + v[2] * v[2] + v[3] * v[3];
  #pragma unroll
  for (int off = 1; off < 64; off <<= 1) {
    s += __shfl_xor(s, off);
    ss += __shfl_xor(ss, off);
  }
  __shared__ float red[8];
  const int lane = tid & 63, wid = tid >> 6;
  if (lane == 0) { red[wid] = s; red[wid + 4] = ss; }
  __syncthreads();
  s = red[0] + red[1] + red[2] + red[3];
  ss = red[4] + red[5] + red[6] + red[7];
  float mu = s * (1.f / 1024.f);
  float var = ss * (1.f / 1024.f) - mu * mu;
  float rs = rsqrtf(var + 1e-5f);
  f32x4 gm = *(const f32x4*)(gamma + tid * 4);
  f32x4 bi = *(const f32x4*)(bias + tid * 4);
  f32x4 o;
  #pragma unroll
  for (int j = 0; j < 4; ++j) o[j] = (v[j] - mu) * rs * gm[j] + bi[j];
  *(f32x4*)(xr + tid * 4) = o;
}

extern "C" void kernel_launch(void* const* d_in, const int* in_sizes, int n_in,
                              void* d_out, int out_size, void* d_ws, size_t ws_size,
                              hipStream_t stream) {
  const float* tokens = (const float*)d_in[0];
  const float* R      = (const float*)d_in[1];
  const float* Wq     = (const float*)d_in[2];
  const float* Wk     = (const float*)d_in[3];
  const float* Wv     = (const float*)d_in[4];
  const float* Wp     = (const float*)d_in[5];
  const float* beta   = (const float*)d_in[6];
  const float* gamma  = (const float*)d_in[7];
  const float* bias   = (const float*)d_in[8];
  float* out = (float*)d_out;
  char* ws = (char*)d_ws;

  unsigned short* tok_bf = (unsigned short*)(ws);                 // 16,777,216 B
  unsigned short* wqkv   = (unsigned short*)(ws + 16777216);      //  6,291,456 B
  unsigned short* wp     = (unsigned short*)(ws + 23068672);      //  2,097,152 B
  float*          logr   = (float*)(ws + 25165824);               // 16,777,216 B
  unsigned short* qb     = (unsigned short*)(ws + 41943040);      // 16,777,216 B
  unsigned short* kb     = (unsigned short*)(ws + 58720256);      // 16,777,216 B
  unsigned short* vt     = (unsigned short*)(ws + 75497472);      // 16,777,216 B
  unsigned short* ao     = tok_bf;  // reuse: tok_bf dead after QKV GEMM

  k_cvt<<<4096, 256, 0, stream>>>(tokens, tok_bf, MROWS * DIM);
  k_cvt<<<512, 256, 0, stream>>>(Wq, wqkv, DIM * DIM);
  k_cvt<<<512, 256, 0, stream>>>(Wk, wqkv + DIM * DIM, DIM * DIM);
  k_cvt<<<512, 256, 0, stream>>>(Wv, wqkv + 2 * DIM * DIM, DIM * DIM);
  k_cvt<<<512, 256, 0, stream>>>(Wp, wp, DIM * DIM);
  k_logr<<<4096, 256, 0, stream>>>(R, logr, beta, LSEQ * LSEQ);

  k_gemm_qkv<<<dim3(64, 24), 256, 0, stream>>>(tok_bf, wqkv, qb, kb, vt);
  k_attn<<<dim3(16, 64), 256, 0, stream>>>(qb, kb, vt, logr, ao);
  k_gemm_proj<<<dim3(64, 8), 256, 0, stream>>>(ao, wp, tokens, out);
  k_ln<<<8192, 256, 0, stream>>>(out, gamma, bias);
}